// Round 1
// baseline (1270.314 us; speedup 1.0000x reference)
//
#include <hip/hip_runtime.h>

// SNN 2-layer LIF forward scan.
// T=1000, B=8192, I=9, H=96, O=3. beta=0.92, thresh=1.0.
// 16 lanes cooperate on one batch element; each lane owns 6 hidden units.
// Weights live in registers; x broadcast by shfl; layer-2 dot reduced by
// shfl_xor butterfly within the 16-lane group. No LDS, no barriers.

#define T_STEPS 1000
#define BATCH   8192
#define NIN     9
#define HID     96
#define NOUT    3
#define GRP     16      // lanes per batch element
#define UPL     6       // hidden units per lane (96/16)

__global__ __launch_bounds__(256) void snn_fwd_kernel(
    const float* __restrict__ x,    // (T,B,9)
    const float* __restrict__ W1,   // (96,9)
    const float* __restrict__ b1,   // (96)
    const float* __restrict__ W2,   // (3,96)
    const float* __restrict__ b2,   // (3)
    float* __restrict__ out)        // spk2 (T,B,3) then mem2 (T,B,3)
{
    const int tid = blockIdx.x * blockDim.x + threadIdx.x;
    const int li  = tid & (GRP - 1);
    const int b   = tid >> 4;              // batch element, 0..8191
    const int u0  = li * UPL;              // first hidden unit this lane owns

    // ---- preload weights into registers ----
    float w1r[UPL][NIN];
    float b1r[UPL];
    float w2r[NOUT][UPL];
    #pragma unroll
    for (int u = 0; u < UPL; ++u) {
        b1r[u] = b1[u0 + u];
        #pragma unroll
        for (int i = 0; i < NIN; ++i)
            w1r[u][i] = W1[(u0 + u) * NIN + i];
    }
    #pragma unroll
    for (int o = 0; o < NOUT; ++o)
        #pragma unroll
        for (int u = 0; u < UPL; ++u)
            w2r[o][u] = W2[o * HID + u0 + u];
    const float b2r0 = b2[0], b2r1 = b2[1], b2r2 = b2[2];

    // ---- state ----
    float mem1[UPL];
    #pragma unroll
    for (int u = 0; u < UPL; ++u) mem1[u] = 0.0f;
    float m20 = 0.0f, m21 = 0.0f, m22 = 0.0f;

    // x offset: clamp lane so lanes 9..15 read a valid (ignored) address
    const int lclamp = (li < NIN) ? li : (NIN - 1);
    size_t xoff = (size_t)b * NIN + lclamp;
    const size_t xstride = (size_t)BATCH * NIN;

    // output addressing (lanes 0..2 -> spk2, lanes 3..5 -> mem2)
    const size_t ostride  = (size_t)BATCH * NOUT;
    const size_t mem_base = (size_t)T_STEPS * ostride;

    for (int t = 0; t < T_STEPS; ++t) {
        // ---- broadcast x[b, 0..8] within the group ----
        float xv = (li < NIN) ? x[xoff] : 0.0f;
        xoff += xstride;

        // ---- layer 1: cur1 = x @ W1.T (ascending-k FMA chain), then + b1 ----
        float acc[UPL];
        #pragma unroll
        for (int u = 0; u < UPL; ++u) acc[u] = 0.0f;
        #pragma unroll
        for (int i = 0; i < NIN; ++i) {
            float xi = __shfl(xv, i, GRP);
            #pragma unroll
            for (int u = 0; u < UPL; ++u)
                acc[u] = __builtin_fmaf(xi, w1r[u][i], acc[u]);
        }

        // ---- leaky update 1 (separate roundings; no FMA contraction) ----
        float spk1[UPL];
        #pragma unroll
        for (int u = 0; u < UPL; ++u) {
            float cur = __fadd_rn(acc[u], b1r[u]);
            float mold = mem1[u];
            float m = __fadd_rn(__fmul_rn(0.92f, mold), cur);
            if (mold > 1.0f) m = __fsub_rn(m, 1.0f);
            mem1[u] = m;
            spk1[u] = (m > 1.0f) ? 1.0f : 0.0f;
        }

        // ---- layer 2: partial dots + butterfly reduce over 16 lanes ----
        float p[NOUT];
        #pragma unroll
        for (int o = 0; o < NOUT; ++o) {
            float s = 0.0f;
            #pragma unroll
            for (int u = 0; u < UPL; ++u)
                s = __builtin_fmaf(spk1[u], w2r[o][u], s);
            // contiguous-pairs tree: offsets 1,2,4,8
            s = __fadd_rn(s, __shfl_xor(s, 1, GRP));
            s = __fadd_rn(s, __shfl_xor(s, 2, GRP));
            s = __fadd_rn(s, __shfl_xor(s, 4, GRP));
            s = __fadd_rn(s, __shfl_xor(s, 8, GRP));
            p[o] = s;
        }

        // ---- leaky update 2 (replicated in all 16 lanes) ----
        float s20, s21, s22;
        {
            float cur = __fadd_rn(p[0], b2r0);
            float m = __fadd_rn(__fmul_rn(0.92f, m20), cur);
            if (m20 > 1.0f) m = __fsub_rn(m, 1.0f);
            m20 = m; s20 = (m > 1.0f) ? 1.0f : 0.0f;
        }
        {
            float cur = __fadd_rn(p[1], b2r1);
            float m = __fadd_rn(__fmul_rn(0.92f, m21), cur);
            if (m21 > 1.0f) m = __fsub_rn(m, 1.0f);
            m21 = m; s21 = (m > 1.0f) ? 1.0f : 0.0f;
        }
        {
            float cur = __fadd_rn(p[2], b2r2);
            float m = __fadd_rn(__fmul_rn(0.92f, m22), cur);
            if (m22 > 1.0f) m = __fsub_rn(m, 1.0f);
            m22 = m; s22 = (m > 1.0f) ? 1.0f : 0.0f;
        }

        // ---- store: lanes 0..2 spk2, lanes 3..5 mem2 ----
        const size_t obase = (size_t)t * ostride + (size_t)b * NOUT;
        if (li < NOUT) {
            float v = (li == 0) ? s20 : (li == 1) ? s21 : s22;
            out[obase + li] = v;
        } else if (li < 2 * NOUT) {
            int c = li - NOUT;
            float v = (c == 0) ? m20 : (c == 1) ? m21 : m22;
            out[mem_base + obase + c] = v;
        }
    }
}

extern "C" void kernel_launch(void* const* d_in, const int* in_sizes, int n_in,
                              void* d_out, int out_size, void* d_ws, size_t ws_size,
                              hipStream_t stream) {
    const float* x  = (const float*)d_in[0];
    const float* W1 = (const float*)d_in[1];
    const float* b1 = (const float*)d_in[2];
    const float* W2 = (const float*)d_in[3];
    const float* b2 = (const float*)d_in[4];
    float* out = (float*)d_out;

    const int total_threads = BATCH * GRP;   // 131072
    dim3 block(256);
    dim3 grid(total_threads / 256);          // 512
    snn_fwd_kernel<<<grid, block, 0, stream>>>(x, W1, b1, W2, b2, out);
}

// Round 2
// 946.485 us; speedup vs baseline: 1.3421x; 1.3421x over previous
//
#include <hip/hip_runtime.h>

// SNN 2-layer LIF forward scan. T=1000, B=8192, I=9, H=96, O=3.
// 16 lanes per batch element, 6 hidden units per lane. Weights in registers.
// R2: direct per-lane x loads (no broadcast shfl), distance-2 x prefetch
// (4 reg buffers, t-loop unrolled x4), spk==rst identity, nontemporal stores.
// Arithmetic order identical to the R1 passing kernel.

#define T_STEPS 1000
#define BATCH   8192
#define NIN     9
#define HID     96
#define NOUT    3
#define GRP     16
#define UPL     6

__device__ __forceinline__ void loadx(float xr[NIN], const float* __restrict__ p) {
    #pragma unroll
    for (int i = 0; i < NIN; ++i) xr[i] = p[i];
}

__global__ __launch_bounds__(256) void snn_fwd_kernel(
    const float* __restrict__ x,    // (T,B,9)
    const float* __restrict__ W1,   // (96,9)
    const float* __restrict__ b1,   // (96)
    const float* __restrict__ W2,   // (3,96)
    const float* __restrict__ b2,   // (3)
    float* __restrict__ out)        // spk2 (T,B,3) then mem2 (T,B,3)
{
    const int tid = blockIdx.x * blockDim.x + threadIdx.x;
    const int li  = tid & (GRP - 1);
    const int b   = tid >> 4;
    const int u0  = li * UPL;

    // ---- preload weights into registers ----
    float w1r[UPL][NIN];
    float b1r[UPL];
    float w2r[NOUT][UPL];
    #pragma unroll
    for (int u = 0; u < UPL; ++u) {
        b1r[u] = b1[u0 + u];
        #pragma unroll
        for (int i = 0; i < NIN; ++i)
            w1r[u][i] = W1[(u0 + u) * NIN + i];
    }
    #pragma unroll
    for (int o = 0; o < NOUT; ++o)
        #pragma unroll
        for (int u = 0; u < UPL; ++u)
            w2r[o][u] = W2[o * HID + u0 + u];
    const float b2r0 = b2[0], b2r1 = b2[1], b2r2 = b2[2];

    // ---- state ----
    float mem1[UPL], spk1[UPL];
    #pragma unroll
    for (int u = 0; u < UPL; ++u) { mem1[u] = 0.0f; spk1[u] = 0.0f; }
    float m20 = 0.0f, m21 = 0.0f, m22 = 0.0f;
    float s20 = 0.0f, s21 = 0.0f, s22 = 0.0f;   // spk2 == rst2 for next step

    const float* xrow = x + (size_t)b * NIN;    // row for this batch element
    const size_t xstride = (size_t)BATCH * NIN;

    const size_t ostride  = (size_t)BATCH * NOUT;
    const size_t mem_base = (size_t)T_STEPS * ostride;
    const size_t obase0   = (size_t)b * NOUT;

    // ---- x prefetch buffers, distance 2 ----
    float x0[NIN], x1[NIN], x2[NIN], x3[NIN];
    loadx(x0, xrow + 0 * xstride);
    loadx(x1, xrow + 1 * xstride);

    #define CLAMP_T(tt) (((tt) < T_STEPS) ? (tt) : (T_STEPS - 1))

    #define STEP(tcur, xr)                                                     \
    do {                                                                       \
        /* layer 1: ascending-k FMA chain, then +b1 (separate rounding) */     \
        float acc[UPL];                                                        \
        _Pragma("unroll")                                                      \
        for (int u = 0; u < UPL; ++u) acc[u] = 0.0f;                           \
        _Pragma("unroll")                                                      \
        for (int i = 0; i < NIN; ++i) {                                        \
            float xi = (xr)[i];                                                \
            _Pragma("unroll")                                                  \
            for (int u = 0; u < UPL; ++u)                                      \
                acc[u] = __builtin_fmaf(xi, w1r[u][i], acc[u]);                \
        }                                                                      \
        /* leaky 1: rst == previous spike (exact identity) */                  \
        _Pragma("unroll")                                                      \
        for (int u = 0; u < UPL; ++u) {                                        \
            float cur = __fadd_rn(acc[u], b1r[u]);                             \
            float m = __fadd_rn(__fmul_rn(0.92f, mem1[u]), cur);               \
            m = __fsub_rn(m, spk1[u]);                                         \
            mem1[u] = m;                                                       \
            spk1[u] = (m > 1.0f) ? 1.0f : 0.0f;                                \
        }                                                                      \
        /* layer 2: per-lane 6-chain + xor butterfly (order as R1) */          \
        float p0, p1, p2;                                                      \
        {                                                                      \
            float s = 0.0f;                                                    \
            _Pragma("unroll")                                                  \
            for (int u = 0; u < UPL; ++u)                                      \
                s = __builtin_fmaf(spk1[u], w2r[0][u], s);                     \
            s = __fadd_rn(s, __shfl_xor(s, 1, GRP));                           \
            s = __fadd_rn(s, __shfl_xor(s, 2, GRP));                           \
            s = __fadd_rn(s, __shfl_xor(s, 4, GRP));                           \
            s = __fadd_rn(s, __shfl_xor(s, 8, GRP));                           \
            p0 = s;                                                            \
        }                                                                      \
        {                                                                      \
            float s = 0.0f;                                                    \
            _Pragma("unroll")                                                  \
            for (int u = 0; u < UPL; ++u)                                      \
                s = __builtin_fmaf(spk1[u], w2r[1][u], s);                     \
            s = __fadd_rn(s, __shfl_xor(s, 1, GRP));                           \
            s = __fadd_rn(s, __shfl_xor(s, 2, GRP));                           \
            s = __fadd_rn(s, __shfl_xor(s, 4, GRP));                           \
            s = __fadd_rn(s, __shfl_xor(s, 8, GRP));                           \
            p1 = s;                                                            \
        }                                                                      \
        {                                                                      \
            float s = 0.0f;                                                    \
            _Pragma("unroll")                                                  \
            for (int u = 0; u < UPL; ++u)                                      \
                s = __builtin_fmaf(spk1[u], w2r[2][u], s);                     \
            s = __fadd_rn(s, __shfl_xor(s, 1, GRP));                           \
            s = __fadd_rn(s, __shfl_xor(s, 2, GRP));                           \
            s = __fadd_rn(s, __shfl_xor(s, 4, GRP));                           \
            s = __fadd_rn(s, __shfl_xor(s, 8, GRP));                           \
            p2 = s;                                                            \
        }                                                                      \
        /* leaky 2 (replicated; rst2 == previous spk2) */                      \
        {                                                                      \
            float cur = __fadd_rn(p0, b2r0);                                   \
            float m = __fadd_rn(__fmul_rn(0.92f, m20), cur);                   \
            m = __fsub_rn(m, s20);                                             \
            m20 = m; s20 = (m > 1.0f) ? 1.0f : 0.0f;                           \
        }                                                                      \
        {                                                                      \
            float cur = __fadd_rn(p1, b2r1);                                   \
            float m = __fadd_rn(__fmul_rn(0.92f, m21), cur);                   \
            m = __fsub_rn(m, s21);                                             \
            m21 = m; s21 = (m > 1.0f) ? 1.0f : 0.0f;                           \
        }                                                                      \
        {                                                                      \
            float cur = __fadd_rn(p2, b2r2);                                   \
            float m = __fadd_rn(__fmul_rn(0.92f, m22), cur);                   \
            m = __fsub_rn(m, s22);                                             \
            m22 = m; s22 = (m > 1.0f) ? 1.0f : 0.0f;                           \
        }                                                                      \
        /* store: lanes 0..2 spk2, lanes 3..5 mem2 */                          \
        const size_t ob = (size_t)(tcur) * ostride + obase0;                   \
        if (li < NOUT) {                                                       \
            float v = (li == 0) ? s20 : (li == 1) ? s21 : s22;                 \
            __builtin_nontemporal_store(v, &out[ob + li]);                     \
        } else if (li < 2 * NOUT) {                                            \
            int c = li - NOUT;                                                 \
            float v = (c == 0) ? m20 : (c == 1) ? m21 : m22;                   \
            __builtin_nontemporal_store(v, &out[mem_base + ob + c]);           \
        }                                                                      \
    } while (0)

    for (int t = 0; t < T_STEPS; t += 4) {
        loadx(x2, xrow + (size_t)CLAMP_T(t + 2) * xstride);
        STEP(t, x0);
        loadx(x3, xrow + (size_t)CLAMP_T(t + 3) * xstride);
        STEP(t + 1, x1);
        loadx(x0, xrow + (size_t)CLAMP_T(t + 4) * xstride);
        STEP(t + 2, x2);
        loadx(x1, xrow + (size_t)CLAMP_T(t + 5) * xstride);
        STEP(t + 3, x3);
    }
    #undef STEP
    #undef CLAMP_T
}

extern "C" void kernel_launch(void* const* d_in, const int* in_sizes, int n_in,
                              void* d_out, int out_size, void* d_ws, size_t ws_size,
                              hipStream_t stream) {
    const float* x  = (const float*)d_in[0];
    const float* W1 = (const float*)d_in[1];
    const float* b1 = (const float*)d_in[2];
    const float* W2 = (const float*)d_in[3];
    const float* b2 = (const float*)d_in[4];
    float* out = (float*)d_out;

    const int total_threads = BATCH * GRP;   // 131072
    dim3 block(256);
    dim3 grid(total_threads / 256);          // 512
    snn_fwd_kernel<<<grid, block, 0, stream>>>(x, W1, b1, W2, b2, out);
}